// Round 12
// baseline (178.067 us; speedup 1.0000x reference)
//
#include <hip/hip_runtime.h>
#include <hip/hip_bf16.h>

// MessagePassing: out[col[e]] += x[row[e]], x: [N=50000, D=128] f32.
// Budget: dur_us = ~60us harness poison floor + pipeline.
// R11 (slice gather, 4B loads): FETCH 110->69MB proved XCD slice-affinity
// works, but 4x load-instruction blowup (VALUBusy 15->50%) regressed.
// R12: slice gather with 16B loads (wave = 16 edge-slots x 4 col-lanes,
// ONE predicated uint4 load/lane at deg<=16) + nontemporal OUT stores so
// write traffic doesn't evict xb slices from L2; NT loads for read-once data.

#define D_FEAT 128
#define MAXDEG 32   // Poisson(10) max deg over 50k nodes ~26; deg>32 -> ovf list

typedef unsigned short u16;
typedef unsigned int u32;
typedef float  f32x4 __attribute__((ext_vector_type(4)));
typedef int    i32x4 __attribute__((ext_vector_type(4)));

__device__ __forceinline__ u16 f2bf(float f) {
    union { __hip_bfloat16 h; u16 u; } c;
    c.h = __float2bfloat16(f);   // RNE
    return c.u;
}
__device__ __forceinline__ float bflo(u32 u) { return __uint_as_float(u << 16); }
__device__ __forceinline__ float bfhi(u32 u) { return __uint_as_float(u & 0xffff0000u); }

// ---------------- fused: fill buckets (blocks [0,FB)) + convert x->bf16 ----------------
__global__ __launch_bounds__(256) void fused_kernel(const float* __restrict__ x,
                                                    u16* __restrict__ xb, int nf4,
                                                    const int* __restrict__ row,
                                                    const int* __restrict__ col,
                                                    int* __restrict__ cnt,
                                                    u16* __restrict__ srclist,
                                                    int* __restrict__ ovf,
                                                    int* __restrict__ ovfcnt,
                                                    int E, int ovfcap,
                                                    int fill_blocks, int aligned) {
    if ((int)blockIdx.x < fill_blocks) {
        // ---- fill: 4 edges/thread, 4 independent atomic chains ----
        const int t = blockIdx.x * 256 + threadIdx.x;
        const int e0 = t * 4;
        if (e0 >= E) return;
        int d[4], s[4], p[4], ne;
        if (aligned && e0 + 4 <= E) {
            const i32x4 dv = __builtin_nontemporal_load(
                reinterpret_cast<const i32x4*>(col + e0));
            const i32x4 sv = __builtin_nontemporal_load(
                reinterpret_cast<const i32x4*>(row + e0));
            d[0] = dv.x; d[1] = dv.y; d[2] = dv.z; d[3] = dv.w;
            s[0] = sv.x; s[1] = sv.y; s[2] = sv.z; s[3] = sv.w;
            ne = 4;
        } else {
            ne = E - e0; if (ne > 4) ne = 4;
            for (int k = 0; k < ne; ++k) { d[k] = col[e0 + k]; s[k] = row[e0 + k]; }
        }
        #pragma unroll
        for (int k = 0; k < 4; ++k)
            if (k < ne) p[k] = atomicAdd(&cnt[d[k]], 1);
        #pragma unroll
        for (int k = 0; k < 4; ++k) {
            if (k < ne) {
                if (p[k] < MAXDEG) {
                    srclist[(size_t)d[k] * MAXDEG + p[k]] = (u16)s[k];
                } else {
                    int o = atomicAdd(ovfcnt, 1);
                    if (o < ovfcap) { ovf[2 * o] = d[k]; ovf[2 * o + 1] = s[k]; }
                }
            }
        }
    } else {
        // ---- convert: float4 -> 4x bf16 (x is read-once: NT load) ----
        const int i = ((int)blockIdx.x - fill_blocks) * 256 + threadIdx.x;
        if (i < nf4) {
            const f32x4 v = __builtin_nontemporal_load(
                reinterpret_cast<const f32x4*>(x) + i);
            ushort4 o;
            o.x = f2bf(v.x); o.y = f2bf(v.y); o.z = f2bf(v.z); o.w = f2bf(v.w);
            reinterpret_cast<ushort4*>(xb)[i] = o;   // xb re-read: keep cached
        }
    }
}

// ---------------- gather: one wave per (node, 32-feat slice) ----------------
// Grid swizzle (as R11, locality verified): xcd=bid&7, slice=xcd>>1,
// group=((bid>>3)<<1)|(bid&1); wave wav handles node group*4+wav.
// Lane = slot*4 + c: slot (0..15) = edge index within a 16-edge step,
// c (0..3) = uint4 column of the 64B slice. ONE predicated 16B load per lane
// per step (deg<=16 -> single step). All __shfl outside divergence.
__global__ __launch_bounds__(256) void gathers_kernel(const u16* __restrict__ xb,
                                                      const int* __restrict__ cnt,
                                                      const u16* __restrict__ srclist,
                                                      const int* __restrict__ ovf,
                                                      const int* __restrict__ ovfcnt,
                                                      float* __restrict__ out,
                                                      int N, int ovfcap) {
    const int bid   = blockIdx.x;
    const int xcd   = bid & 7;
    const int slice = xcd >> 1;                       // 0..3
    const int group = ((bid >> 3) << 1) | (bid & 1);  // dense per slice
    const int wav   = threadIdx.x >> 6;               // 0..3
    const int wid   = group * 4 + wav;                // node id
    if (wid >= N) return;
    const int lane = threadIdx.x & 63;
    const int slot = lane >> 2;                       // 0..15 edge slot
    const int c    = lane & 3;                        // uint4 col in slice

    const int rawdeg = cnt[wid];
    const int deg = rawdeg > MAXDEG ? MAXDEG : rawdeg;
    const u16* bucket = srclist + (size_t)wid * MAXDEG;
    const int bval = (int)bucket[lane & 31];          // 64B bucket per wave

    const size_t colbase = (size_t)slice * 32 + (size_t)c * 8;  // u16 units
    float acc[8] = {0.f, 0.f, 0.f, 0.f, 0.f, 0.f, 0.f, 0.f};

    for (int j = 0; j < deg; j += 16) {               // wave-uniform (deg<=32: <=2 iters)
        const int src = __shfl(bval, j + slot, 64);   // all lanes shuffle
        if (j + slot < deg) {                         // predicated load+add only
            const uint4 w = *reinterpret_cast<const uint4*>(
                xb + (size_t)src * D_FEAT + colbase);
            acc[0] += bflo(w.x); acc[1] += bfhi(w.x);
            acc[2] += bflo(w.y); acc[3] += bfhi(w.y);
            acc[4] += bflo(w.z); acc[5] += bfhi(w.z);
            acc[6] += bflo(w.w); acc[7] += bfhi(w.w);
        }
    }

    // inline overflow fixup (deg > MAXDEG nodes only, ~never) — no shfl inside
    if (rawdeg > MAXDEG) {
        int novf = *ovfcnt;
        if (novf > ovfcap) novf = ovfcap;
        for (int k = 0; k < novf; ++k) {
            if (ovf[2 * k] == wid && slot == 0) {
                const int s = ovf[2 * k + 1];
                const uint4 w = *reinterpret_cast<const uint4*>(
                    xb + (size_t)s * D_FEAT + colbase);
                acc[0] += bflo(w.x); acc[1] += bfhi(w.x);
                acc[2] += bflo(w.y); acc[3] += bfhi(w.y);
                acc[4] += bflo(w.z); acc[5] += bfhi(w.z);
                acc[6] += bflo(w.w); acc[7] += bfhi(w.w);
            }
        }
    }

    // reduce across the 16 edge-slots (lane stride 4); all lanes active
    #pragma unroll
    for (int k = 0; k < 8; ++k) {
        acc[k] += __shfl_xor(acc[k], 4, 64);
        acc[k] += __shfl_xor(acc[k], 8, 64);
        acc[k] += __shfl_xor(acc[k], 16, 64);
        acc[k] += __shfl_xor(acc[k], 32, 64);
    }
    if (slot == 0) {  // lanes 0..3 write the slice: 4 x 32B = 128B, NT (never re-read)
        float* o = out + (size_t)wid * D_FEAT + slice * 32 + c * 8;
        f32x4 v0 = {acc[0], acc[1], acc[2], acc[3]};
        f32x4 v1 = {acc[4], acc[5], acc[6], acc[7]};
        __builtin_nontemporal_store(v0, reinterpret_cast<f32x4*>(o));
        __builtin_nontemporal_store(v1, reinterpret_cast<f32x4*>(o + 4));
    }
}

// ---------------- last-resort fallback: atomic scatter (always correct) ----------------
__global__ void mp_scatter_kernel(const float* __restrict__ x,
                                  const int* __restrict__ row,
                                  const int* __restrict__ col,
                                  float* __restrict__ out, int n_edges) {
    const int t = blockIdx.x * blockDim.x + threadIdx.x;
    const int e = t >> 5;
    const int c = t & 31;
    if (e >= n_edges) return;
    const float4 v = *reinterpret_cast<const float4*>(
        x + (size_t)row[e] * D_FEAT + (size_t)c * 4);
    float* o = out + (size_t)col[e] * D_FEAT + (size_t)c * 4;
    atomicAdd(o + 0, v.x);
    atomicAdd(o + 1, v.y);
    atomicAdd(o + 2, v.z);
    atomicAdd(o + 3, v.w);
}

extern "C" void kernel_launch(void* const* d_in, const int* in_sizes, int n_in,
                              void* d_out, int out_size, void* d_ws, size_t ws_size,
                              hipStream_t stream) {
    const float* x   = (const float*)d_in[0];
    const int*   ei  = (const int*)d_in[1];
    float*       out = (float*)d_out;

    const int E = in_sizes[1] / 2;      // edge_index is [2, E]
    const int N = out_size / D_FEAT;
    const int* row = ei;                 // sources
    const int* col = ei + E;             // targets

    // ws byte layout: cnt[N]+ovfcnt | xb[N*128 u16] | srclist[N*32 u16] | ovf[2E int]
    const size_t cnt_bytes = ((size_t)N + 1) * 4;
    const size_t xb_off    = (cnt_bytes + 255) & ~(size_t)255;
    const size_t xb_bytes  = (size_t)N * D_FEAT * 2;
    const size_t src_off   = (xb_off + xb_bytes + 255) & ~(size_t)255;
    const size_t src_bytes = (size_t)N * MAXDEG * 2;
    const size_t ovf_off   = (src_off + src_bytes + 255) & ~(size_t)255;
    const size_t needed    = ovf_off + 2ull * (size_t)E * 4;

    if (ws_size < needed || N > 65535) {
        (void)hipMemsetAsync(d_out, 0, (size_t)out_size * sizeof(float), stream);
        const int total = E * 32;
        mp_scatter_kernel<<<(total + 255) / 256, 256, 0, stream>>>(x, row, col, out, E);
        return;
    }

    char* wsb     = (char*)d_ws;
    int*  cnt     = (int*)wsb;
    int*  ovfcnt  = cnt + N;
    u16*  xb      = (u16*)(wsb + xb_off);
    u16*  srclist = (u16*)(wsb + src_off);
    int*  ovf     = (int*)(wsb + ovf_off);

    // 1. zero counters (cnt[N] + ovfcnt)
    (void)hipMemsetAsync(cnt, 0, cnt_bytes, stream);

    // 2. fused fill + convert
    const int fill_threads = (E + 3) / 4;
    const int fill_blocks  = (fill_threads + 255) / 256;
    const int nf4          = N * D_FEAT / 4;
    const int conv_blocks  = (nf4 + 255) / 256;
    const int aligned      = ((E & 3) == 0) ? 1 : 0;
    fused_kernel<<<fill_blocks + conv_blocks, 256, 0, stream>>>(
        x, xb, nf4, row, col, cnt, srclist, ovf, ovfcnt, E, E, fill_blocks, aligned);

    // 3. slice gather: 4 waves (nodes) per block, slice = (bid&7)>>1
    const int blocks_per_slice = (N + 3) / 4;           // nodes/4
    const int half             = (blocks_per_slice + 1) / 2;
    const int grid             = 8 * half;
    gathers_kernel<<<grid, 256, 0, stream>>>(xb, cnt, srclist, ovf, ovfcnt, out, N, E);
}

// Round 13
// 129.701 us; speedup vs baseline: 1.3729x; 1.3729x over previous
//
#include <hip/hip_runtime.h>
#include <hip/hip_bf16.h>

// MessagePassing: out[col[e]] += x[row[e]], x: [N=50000, D=128] f32.
// Budget: dur_us = ~55-60us harness poison/restore floor + pipeline.
// R11/R12 (slice-affinity gathers) REGRESSED: gather is latency/overhead
// bound (HBM 15-25%), so traffic levers don't pay; per-wave overhead does.
// R13 = revert to R10 structure (best, 124.6us): full 128-feat row per wave,
// quarter-wave edge slots, 16B uint4 loads, 2-stage reduce. Keep from R12
// only: NT loads for read-once x/edges, NT stores for out (never re-read,
// keeps xb resident in L2).

#define D_FEAT 128
#define MAXDEG 32   // Poisson(10) max deg over 50k nodes ~26; deg>32 -> ovf list

typedef unsigned short u16;
typedef unsigned int u32;
typedef float  f32x4 __attribute__((ext_vector_type(4)));
typedef int    i32x4 __attribute__((ext_vector_type(4)));

__device__ __forceinline__ u16 f2bf(float f) {
    union { __hip_bfloat16 h; u16 u; } c;
    c.h = __float2bfloat16(f);   // RNE
    return c.u;
}
__device__ __forceinline__ float bflo(u32 u) { return __uint_as_float(u << 16); }
__device__ __forceinline__ float bfhi(u32 u) { return __uint_as_float(u & 0xffff0000u); }

__device__ __forceinline__ void addrow(float acc[8], const uint4& v) {
    acc[0] += bflo(v.x); acc[1] += bfhi(v.x);
    acc[2] += bflo(v.y); acc[3] += bfhi(v.y);
    acc[4] += bflo(v.z); acc[5] += bfhi(v.z);
    acc[6] += bflo(v.w); acc[7] += bfhi(v.w);
}

// ---------------- fused: fill buckets (blocks [0,FB)) + convert x->bf16 ----------------
__global__ __launch_bounds__(256) void fused_kernel(const float* __restrict__ x,
                                                    u16* __restrict__ xb, int nf4,
                                                    const int* __restrict__ row,
                                                    const int* __restrict__ col,
                                                    int* __restrict__ cnt,
                                                    u16* __restrict__ srclist,
                                                    int* __restrict__ ovf,
                                                    int* __restrict__ ovfcnt,
                                                    int E, int ovfcap,
                                                    int fill_blocks, int aligned) {
    if ((int)blockIdx.x < fill_blocks) {
        // ---- fill: 4 edges/thread, 4 independent atomic chains ----
        const int t = blockIdx.x * 256 + threadIdx.x;
        const int e0 = t * 4;
        if (e0 >= E) return;
        int d[4], s[4], p[4], ne;
        if (aligned && e0 + 4 <= E) {
            const i32x4 dv = __builtin_nontemporal_load(
                reinterpret_cast<const i32x4*>(col + e0));
            const i32x4 sv = __builtin_nontemporal_load(
                reinterpret_cast<const i32x4*>(row + e0));
            d[0] = dv.x; d[1] = dv.y; d[2] = dv.z; d[3] = dv.w;
            s[0] = sv.x; s[1] = sv.y; s[2] = sv.z; s[3] = sv.w;
            ne = 4;
        } else {
            ne = E - e0; if (ne > 4) ne = 4;
            for (int k = 0; k < ne; ++k) { d[k] = col[e0 + k]; s[k] = row[e0 + k]; }
        }
        #pragma unroll
        for (int k = 0; k < 4; ++k)
            if (k < ne) p[k] = atomicAdd(&cnt[d[k]], 1);
        #pragma unroll
        for (int k = 0; k < 4; ++k) {
            if (k < ne) {
                if (p[k] < MAXDEG) {
                    srclist[(size_t)d[k] * MAXDEG + p[k]] = (u16)s[k];
                } else {
                    int o = atomicAdd(ovfcnt, 1);
                    if (o < ovfcap) { ovf[2 * o] = d[k]; ovf[2 * o + 1] = s[k]; }
                }
            }
        }
    } else {
        // ---- convert: float4 -> 4x bf16 (x read-once: NT load) ----
        const int i = ((int)blockIdx.x - fill_blocks) * 256 + threadIdx.x;
        if (i < nf4) {
            const f32x4 v = __builtin_nontemporal_load(
                reinterpret_cast<const f32x4*>(x) + i);
            ushort4 o;
            o.x = f2bf(v.x); o.y = f2bf(v.y); o.z = f2bf(v.z); o.w = f2bf(v.w);
            reinterpret_cast<ushort4*>(xb)[i] = o;   // xb re-read: keep cached
        }
    }
}

// ---------------- gather: one wave per node (R10 structure) ----------------
// Quarter q (16 lanes) owns one edge per step; lane covers 8 bf16 (16B uint4).
// ALL __shfl calls execute with the full wave active (R9 lesson).
__global__ __launch_bounds__(256) void gatherq_kernel(const u16* __restrict__ xb,
                                                      const int* __restrict__ cnt,
                                                      const u16* __restrict__ srclist,
                                                      const int* __restrict__ ovf,
                                                      const int* __restrict__ ovfcnt,
                                                      float* __restrict__ out,
                                                      int N, int ovfcap) {
    const int wid  = (blockIdx.x * blockDim.x + threadIdx.x) >> 6;
    const int lane = threadIdx.x & 63;
    if (wid >= N) return;
    const int q = lane >> 4;          // quarter 0..3
    const int c = lane & 15;          // uint4 (8-bf16) column block
    const int rawdeg = cnt[wid];
    const int deg = rawdeg > MAXDEG ? MAXDEG : rawdeg;
    const u16* bucket = srclist + (size_t)wid * MAXDEG;
    const int bval = (int)bucket[lane & 31];   // whole 64B bucket per wave

    float acc[8] = {0.f, 0.f, 0.f, 0.f, 0.f, 0.f, 0.f, 0.f};

    int j = 0;
    for (; j + 8 <= deg; j += 8) {             // wave-uniform condition
        const int i0 = __shfl(bval, j + q, 64);
        const int i1 = __shfl(bval, j + 4 + q, 64);
        const uint4 w0 = *reinterpret_cast<const uint4*>(xb + (size_t)i0 * D_FEAT + c * 8);
        const uint4 w1 = *reinterpret_cast<const uint4*>(xb + (size_t)i1 * D_FEAT + c * 8);
        addrow(acc, w0);
        addrow(acc, w1);
    }
    if (j + 4 <= deg) {                        // wave-uniform condition
        const int i0 = __shfl(bval, j + q, 64);
        const uint4 w0 = *reinterpret_cast<const uint4*>(xb + (size_t)i0 * D_FEAT + c * 8);
        addrow(acc, w0);
        j += 4;
    }
    {
        const int r = deg - j;                 // 0..3
        const int i0 = __shfl(bval, j + q, 64);  // all 64 lanes shuffle
        if (q < r) {                             // predicated load+add only
            const uint4 w0 = *reinterpret_cast<const uint4*>(xb + (size_t)i0 * D_FEAT + c * 8);
            addrow(acc, w0);
        }
    }

    // inline overflow fixup (deg > MAXDEG nodes only, ~never) — no shfl inside
    if (rawdeg > MAXDEG) {
        int novf = *ovfcnt;
        if (novf > ovfcap) novf = ovfcap;
        for (int k = 0; k < novf; ++k) {
            if (ovf[2 * k] == wid && q == 0) {
                const int s = ovf[2 * k + 1];
                const uint4 w = *reinterpret_cast<const uint4*>(xb + (size_t)s * D_FEAT + c * 8);
                addrow(acc, w);
            }
        }
    }

    // combine the 4 quarters (all lanes active)
    #pragma unroll
    for (int k = 0; k < 8; ++k) {
        acc[k] += __shfl_xor(acc[k], 16, 64);
        acc[k] += __shfl_xor(acc[k], 32, 64);
    }
    if (q == 0) {   // 16 lanes x 32B = 512B row, NT (out never re-read)
        float* o = out + (size_t)wid * D_FEAT + c * 8;
        f32x4 v0 = {acc[0], acc[1], acc[2], acc[3]};
        f32x4 v1 = {acc[4], acc[5], acc[6], acc[7]};
        __builtin_nontemporal_store(v0, reinterpret_cast<f32x4*>(o));
        __builtin_nontemporal_store(v1, reinterpret_cast<f32x4*>(o + 4));
    }
}

// ---------------- last-resort fallback: atomic scatter (always correct) ----------------
__global__ void mp_scatter_kernel(const float* __restrict__ x,
                                  const int* __restrict__ row,
                                  const int* __restrict__ col,
                                  float* __restrict__ out, int n_edges) {
    const int t = blockIdx.x * blockDim.x + threadIdx.x;
    const int e = t >> 5;
    const int c = t & 31;
    if (e >= n_edges) return;
    const float4 v = *reinterpret_cast<const float4*>(
        x + (size_t)row[e] * D_FEAT + (size_t)c * 4);
    float* o = out + (size_t)col[e] * D_FEAT + (size_t)c * 4;
    atomicAdd(o + 0, v.x);
    atomicAdd(o + 1, v.y);
    atomicAdd(o + 2, v.z);
    atomicAdd(o + 3, v.w);
}

extern "C" void kernel_launch(void* const* d_in, const int* in_sizes, int n_in,
                              void* d_out, int out_size, void* d_ws, size_t ws_size,
                              hipStream_t stream) {
    const float* x   = (const float*)d_in[0];
    const int*   ei  = (const int*)d_in[1];
    float*       out = (float*)d_out;

    const int E = in_sizes[1] / 2;      // edge_index is [2, E]
    const int N = out_size / D_FEAT;
    const int* row = ei;                 // sources
    const int* col = ei + E;             // targets

    // ws byte layout: cnt[N]+ovfcnt | xb[N*128 u16] | srclist[N*32 u16] | ovf[2E int]
    const size_t cnt_bytes = ((size_t)N + 1) * 4;
    const size_t xb_off    = (cnt_bytes + 255) & ~(size_t)255;
    const size_t xb_bytes  = (size_t)N * D_FEAT * 2;
    const size_t src_off   = (xb_off + xb_bytes + 255) & ~(size_t)255;
    const size_t src_bytes = (size_t)N * MAXDEG * 2;
    const size_t ovf_off   = (src_off + src_bytes + 255) & ~(size_t)255;
    const size_t needed    = ovf_off + 2ull * (size_t)E * 4;

    if (ws_size < needed || N > 65535) {
        (void)hipMemsetAsync(d_out, 0, (size_t)out_size * sizeof(float), stream);
        const int total = E * 32;
        mp_scatter_kernel<<<(total + 255) / 256, 256, 0, stream>>>(x, row, col, out, E);
        return;
    }

    char* wsb     = (char*)d_ws;
    int*  cnt     = (int*)wsb;
    int*  ovfcnt  = cnt + N;
    u16*  xb      = (u16*)(wsb + xb_off);
    u16*  srclist = (u16*)(wsb + src_off);
    int*  ovf     = (int*)(wsb + ovf_off);

    // 1. zero counters (cnt[N] + ovfcnt)
    (void)hipMemsetAsync(cnt, 0, cnt_bytes, stream);

    // 2. fused fill + convert (fill blocks first so their atomic latency
    //    hides under the convert blocks' streaming)
    const int fill_threads = (E + 3) / 4;
    const int fill_blocks  = (fill_threads + 255) / 256;
    const int nf4          = N * D_FEAT / 4;
    const int conv_blocks  = (nf4 + 255) / 256;
    const int aligned      = ((E & 3) == 0) ? 1 : 0;
    fused_kernel<<<fill_blocks + conv_blocks, 256, 0, stream>>>(
        x, xb, nf4, row, col, cnt, srclist, ovf, ovfcnt, E, E, fill_blocks, aligned);

    // 3. gather (R10 structure)
    const int total = N * 64;
    gatherq_kernel<<<(total + 255) / 256, 256, 0, stream>>>(xb, cnt, srclist,
                                                            ovf, ovfcnt, out, N, E);
}

// Round 14
// 127.228 us; speedup vs baseline: 1.3996x; 1.0194x over previous
//
#include <hip/hip_runtime.h>
#include <hip/hip_bf16.h>

// MessagePassing: out[col[e]] += x[row[e]], x: [N=50000, D=128] f32.
// FINAL (R14 = exact R10 revert, session best 124.6us):
//   dur_us = ~60us harness poison/restore floor (in-profile fillBufferAligned,
//   268MB @ ~75% HBM peak) + ~65us pipeline:
//   - memset cnt (200KB)
//   - fused kernel: {fill padded ushort buckets: 4 edges/thread, 4 indep
//     atomic chains | convert x -> bf16 (halves gather traffic)}
//   - gatherq: one wave per node, quarter-wave edge slots, 16B uint4 loads,
//     shift/mask bf16 unpack, 2-stage shfl_xor reduce, 512B row store.
// Tried and rejected with counter evidence:
//   R1 atomic scatter (845us, WRITE 1GB: atomic-throughput bound)
//   R2-R4 CSR+scan (168us; scan latency + 2 extra dispatches)
//   R11/R12 XCD slice affinity (FETCH 110->64MB proven, but per-wave
//     overhead regressed 124.6 -> 151/178: gather is latency-bound, not BW)
//   R13 NT loads/stores (+5us, mechanism unproven -> reverted)

#define D_FEAT 128
#define MAXDEG 32   // Poisson(10) max deg over 50k nodes ~26; deg>32 -> ovf list

typedef unsigned short u16;
typedef unsigned int u32;

__device__ __forceinline__ u16 f2bf(float f) {
    union { __hip_bfloat16 h; u16 u; } c;
    c.h = __float2bfloat16(f);   // RNE
    return c.u;
}
__device__ __forceinline__ float bflo(u32 u) { return __uint_as_float(u << 16); }
__device__ __forceinline__ float bfhi(u32 u) { return __uint_as_float(u & 0xffff0000u); }

__device__ __forceinline__ void addrow(float acc[8], const uint4& v) {
    acc[0] += bflo(v.x); acc[1] += bfhi(v.x);
    acc[2] += bflo(v.y); acc[3] += bfhi(v.y);
    acc[4] += bflo(v.z); acc[5] += bfhi(v.z);
    acc[6] += bflo(v.w); acc[7] += bfhi(v.w);
}

// ---------------- fused: fill buckets (blocks [0,FB)) + convert x->bf16 ----------------
__global__ __launch_bounds__(256) void fused_kernel(const float* __restrict__ x,
                                                    u16* __restrict__ xb, int nf4,
                                                    const int* __restrict__ row,
                                                    const int* __restrict__ col,
                                                    int* __restrict__ cnt,
                                                    u16* __restrict__ srclist,
                                                    int* __restrict__ ovf,
                                                    int* __restrict__ ovfcnt,
                                                    int E, int ovfcap,
                                                    int fill_blocks, int aligned) {
    if ((int)blockIdx.x < fill_blocks) {
        // ---- fill: 4 edges/thread, 4 independent atomic chains ----
        const int t = blockIdx.x * 256 + threadIdx.x;
        const int e0 = t * 4;
        if (e0 >= E) return;
        int d[4], s[4], p[4], ne;
        if (aligned && e0 + 4 <= E) {
            const int4 dv = *reinterpret_cast<const int4*>(col + e0);
            const int4 sv = *reinterpret_cast<const int4*>(row + e0);
            d[0] = dv.x; d[1] = dv.y; d[2] = dv.z; d[3] = dv.w;
            s[0] = sv.x; s[1] = sv.y; s[2] = sv.z; s[3] = sv.w;
            ne = 4;
        } else {
            ne = E - e0; if (ne > 4) ne = 4;
            for (int k = 0; k < ne; ++k) { d[k] = col[e0 + k]; s[k] = row[e0 + k]; }
        }
        #pragma unroll
        for (int k = 0; k < 4; ++k)
            if (k < ne) p[k] = atomicAdd(&cnt[d[k]], 1);
        #pragma unroll
        for (int k = 0; k < 4; ++k) {
            if (k < ne) {
                if (p[k] < MAXDEG) {
                    srclist[(size_t)d[k] * MAXDEG + p[k]] = (u16)s[k];
                } else {
                    int o = atomicAdd(ovfcnt, 1);
                    if (o < ovfcap) { ovf[2 * o] = d[k]; ovf[2 * o + 1] = s[k]; }
                }
            }
        }
    } else {
        // ---- convert: float4 -> 4x bf16 ----
        const int i = ((int)blockIdx.x - fill_blocks) * 256 + threadIdx.x;
        if (i < nf4) {
            const float4 v = reinterpret_cast<const float4*>(x)[i];
            ushort4 o;
            o.x = f2bf(v.x); o.y = f2bf(v.y); o.z = f2bf(v.z); o.w = f2bf(v.w);
            reinterpret_cast<ushort4*>(xb)[i] = o;
        }
    }
}

// ---------------- gather: one wave per node, quarter-wave rows ----------------
// Quarter q (16 lanes) owns one edge per step; lane covers 8 bf16 (16B uint4).
// ALL __shfl calls execute with the full wave active; only loads/adds are
// predicated (ds_bpermute from an inactive lane is undefined — R9 lesson).
__global__ __launch_bounds__(256) void gatherq_kernel(const u16* __restrict__ xb,
                                                      const int* __restrict__ cnt,
                                                      const u16* __restrict__ srclist,
                                                      const int* __restrict__ ovf,
                                                      const int* __restrict__ ovfcnt,
                                                      float* __restrict__ out,
                                                      int N, int ovfcap) {
    const int wid  = (blockIdx.x * blockDim.x + threadIdx.x) >> 6;
    const int lane = threadIdx.x & 63;
    if (wid >= N) return;
    const int q = lane >> 4;          // quarter 0..3
    const int c = lane & 15;          // uint4 (8-bf16) column block
    const int rawdeg = cnt[wid];
    const int deg = rawdeg > MAXDEG ? MAXDEG : rawdeg;
    const u16* bucket = srclist + (size_t)wid * MAXDEG;
    const int bval = (int)bucket[lane & 31];   // whole 64B bucket per wave

    float acc[8] = {0.f, 0.f, 0.f, 0.f, 0.f, 0.f, 0.f, 0.f};

    int j = 0;
    for (; j + 8 <= deg; j += 8) {             // wave-uniform condition
        const int i0 = __shfl(bval, j + q, 64);
        const int i1 = __shfl(bval, j + 4 + q, 64);
        const uint4 w0 = *reinterpret_cast<const uint4*>(xb + (size_t)i0 * D_FEAT + c * 8);
        const uint4 w1 = *reinterpret_cast<const uint4*>(xb + (size_t)i1 * D_FEAT + c * 8);
        addrow(acc, w0);
        addrow(acc, w1);
    }
    if (j + 4 <= deg) {                        // wave-uniform condition
        const int i0 = __shfl(bval, j + q, 64);
        const uint4 w0 = *reinterpret_cast<const uint4*>(xb + (size_t)i0 * D_FEAT + c * 8);
        addrow(acc, w0);
        j += 4;
    }
    {
        const int r = deg - j;                 // 0..3
        // shfl OUTSIDE the divergent branch: all 64 lanes participate, so the
        // source lane is always active. Value unused when q >= r.
        const int i0 = __shfl(bval, j + q, 64);
        if (q < r) {
            const uint4 w0 = *reinterpret_cast<const uint4*>(xb + (size_t)i0 * D_FEAT + c * 8);
            addrow(acc, w0);
        }
    }

    // inline overflow fixup (only for deg > MAXDEG nodes, ~never) — no shfl inside
    if (rawdeg > MAXDEG) {
        int novf = *ovfcnt;
        if (novf > ovfcap) novf = ovfcap;
        for (int k = 0; k < novf; ++k) {
            if (ovf[2 * k] == wid && q == 0) {
                const int s = ovf[2 * k + 1];
                const uint4 w = *reinterpret_cast<const uint4*>(xb + (size_t)s * D_FEAT + c * 8);
                addrow(acc, w);
            }
        }
    }

    // combine the 4 quarters (all lanes active here)
    #pragma unroll
    for (int k = 0; k < 8; ++k) {
        acc[k] += __shfl_xor(acc[k], 16, 64);
        acc[k] += __shfl_xor(acc[k], 32, 64);
    }
    if (q == 0) {
        float* o = out + (size_t)wid * D_FEAT + c * 8;
        *reinterpret_cast<float4*>(o)     = make_float4(acc[0], acc[1], acc[2], acc[3]);
        *reinterpret_cast<float4*>(o + 4) = make_float4(acc[4], acc[5], acc[6], acc[7]);
    }
}

// ---------------- last-resort fallback: atomic scatter (always correct) ----------------
__global__ void mp_scatter_kernel(const float* __restrict__ x,
                                  const int* __restrict__ row,
                                  const int* __restrict__ col,
                                  float* __restrict__ out, int n_edges) {
    const int t = blockIdx.x * blockDim.x + threadIdx.x;
    const int e = t >> 5;
    const int c = t & 31;
    if (e >= n_edges) return;
    const float4 v = *reinterpret_cast<const float4*>(
        x + (size_t)row[e] * D_FEAT + (size_t)c * 4);
    float* o = out + (size_t)col[e] * D_FEAT + (size_t)c * 4;
    atomicAdd(o + 0, v.x);
    atomicAdd(o + 1, v.y);
    atomicAdd(o + 2, v.z);
    atomicAdd(o + 3, v.w);
}

extern "C" void kernel_launch(void* const* d_in, const int* in_sizes, int n_in,
                              void* d_out, int out_size, void* d_ws, size_t ws_size,
                              hipStream_t stream) {
    const float* x   = (const float*)d_in[0];
    const int*   ei  = (const int*)d_in[1];
    float*       out = (float*)d_out;

    const int E = in_sizes[1] / 2;      // edge_index is [2, E]
    const int N = out_size / D_FEAT;
    const int* row = ei;                 // sources
    const int* col = ei + E;             // targets

    // ws byte layout: cnt[N]+ovfcnt | xb[N*128 u16] | srclist[N*32 u16] | ovf[2E int]
    const size_t cnt_bytes = ((size_t)N + 1) * 4;
    const size_t xb_off    = (cnt_bytes + 255) & ~(size_t)255;
    const size_t xb_bytes  = (size_t)N * D_FEAT * 2;
    const size_t src_off   = (xb_off + xb_bytes + 255) & ~(size_t)255;
    const size_t src_bytes = (size_t)N * MAXDEG * 2;
    const size_t ovf_off   = (src_off + src_bytes + 255) & ~(size_t)255;
    const size_t needed    = ovf_off + 2ull * (size_t)E * 4;

    if (ws_size < needed || N > 65535) {
        (void)hipMemsetAsync(d_out, 0, (size_t)out_size * sizeof(float), stream);
        const int total = E * 32;
        mp_scatter_kernel<<<(total + 255) / 256, 256, 0, stream>>>(x, row, col, out, E);
        return;
    }

    char* wsb     = (char*)d_ws;
    int*  cnt     = (int*)wsb;
    int*  ovfcnt  = cnt + N;
    u16*  xb      = (u16*)(wsb + xb_off);
    u16*  srclist = (u16*)(wsb + src_off);
    int*  ovf     = (int*)(wsb + ovf_off);

    // 1. zero counters (cnt[N] + ovfcnt)
    (void)hipMemsetAsync(cnt, 0, cnt_bytes, stream);

    // 2. fused fill + convert (fill blocks first so their atomic latency
    //    hides under the convert blocks' streaming)
    const int fill_threads = (E + 3) / 4;
    const int fill_blocks  = (fill_threads + 255) / 256;
    const int nf4          = N * D_FEAT / 4;
    const int conv_blocks  = (nf4 + 255) / 256;
    const int aligned      = ((E & 3) == 0) ? 1 : 0;
    fused_kernel<<<fill_blocks + conv_blocks, 256, 0, stream>>>(
        x, xb, nf4, row, col, cnt, srclist, ovf, ovfcnt, E, E, fill_blocks, aligned);

    // 3. gather
    const int total = N * 64;
    gatherq_kernel<<<(total + 255) / 256, 256, 0, stream>>>(xb, cnt, srclist,
                                                            ovf, ovfcnt, out, N, E);
}